// Round 1
// baseline (355.060 us; speedup 1.0000x reference)
//
#include <hip/hip_runtime.h>
#include <math.h>

#define NVARS 11
#define NUMT  100
#define NOBS  10
#define MAXIT 50

// workspace layout (floats)
#define E_OFF    0      // inv_init[:11,11:17]  11x6
#define F_OFF    66     // inv_opt[:11,:11]     11x11
#define G4_OFF   187    // inv_opt[:11,11:15]   11x4
#define GP_OFF   231    // P^T P                11x11
#define GPD_OFF  352    // Pd^T Pd
#define GPDD_OFF 473    // Pdd^T Pdd
#define WS_FLOATS 594

__device__ void gj_inv(double (*aug)[34], int N, double* fac, int* piv, int tid, int nthr)
{
    for (int k = 0; k < N; ++k) {
        if (tid == 0) {
            int p = k; double best = fabs(aug[k][k]);
            for (int r = k + 1; r < N; ++r) { double v = fabs(aug[r][k]); if (v > best) { best = v; p = r; } }
            *piv = p;
        }
        __syncthreads();
        int p = *piv;
        if (p != k) {
            for (int c = tid; c < 2 * N; c += nthr) { double t = aug[k][c]; aug[k][c] = aug[p][c]; aug[p][c] = t; }
        }
        __syncthreads();
        double pv = aug[k][k];
        __syncthreads();
        for (int c = tid; c < 2 * N; c += nthr) aug[k][c] /= pv;
        __syncthreads();
        if (tid < N) fac[tid] = aug[tid][k];
        __syncthreads();
        for (int idx = tid; idx < N * 2 * N; idx += nthr) {
            int r = idx / (2 * N), c = idx % (2 * N);
            if (r != k) aug[r][c] -= fac[r] * aug[k][c];
        }
        __syncthreads();
    }
}

__global__ __launch_bounds__(128) void setup_kernel(const float* __restrict__ P,
                                                    const float* __restrict__ Pd,
                                                    const float* __restrict__ Pdd,
                                                    float* __restrict__ ws)
{
    __shared__ double G[3][NVARS][NVARS];
    __shared__ double aug[17][34];
    __shared__ double fac[17];
    __shared__ int piv;
    const int tid = threadIdx.x, nthr = 128;

    // Gram matrices in fp64
    for (int idx = tid; idx < 3 * 121; idx += nthr) {
        int q = idx / 121, rem = idx % 121, r = rem / 11, c = rem % 11;
        const float* B = (q == 0) ? P : (q == 1) ? Pd : Pdd;
        double s = 0.0;
        for (int t = 0; t < NUMT; ++t) s += (double)B[t * 11 + r] * (double)B[t * 11 + c];
        G[q][r][c] = s;
    }
    __syncthreads();
    for (int idx = tid; idx < 3 * 121; idx += nthr) ws[GP_OFF + idx] = (float)((&G[0][0][0])[idx]);

    // ---- inv_init: KKT [Pdd^T Pdd, A^T; A, 0], A rows = P[0],Pd[0],P[99],Pd[99],P[49],P[74]
    for (int idx = tid; idx < 17 * 34; idx += nthr) aug[idx / 34][idx % 34] = 0.0;
    __syncthreads();
    for (int idx = tid; idx < 121; idx += nthr) aug[idx / 11][idx % 11] = G[2][idx / 11][idx % 11];
    if (tid < 66) {
        int r = tid / 11, j = tid % 11;
        const float* src = (r == 0) ? P : (r == 1) ? Pd : (r == 2) ? (P + 99 * 11) : (r == 3) ? (Pd + 99 * 11)
                           : (r == 4) ? (P + 49 * 11) : (P + 74 * 11);
        double v = (double)src[j];
        aug[j][11 + r] = v;
        aug[11 + r][j] = v;
    }
    if (tid < 17) aug[tid][17 + tid] = 1.0;
    __syncthreads();
    gj_inv(aug, 17, fac, &piv, tid, nthr);
    if (tid < 66) { int j = tid / 6, k = tid % 6; ws[E_OFF + tid] = (float)aug[j][17 + 11 + k]; }
    __syncthreads();

    // ---- inv_opt: cost = 11*GP + GPd + GPdd + I ; A rows = P[0],Pd[0],P[99],Pd[99]
    for (int idx = tid; idx < 17 * 34; idx += nthr) aug[idx / 34][idx % 34] = 0.0;
    __syncthreads();
    for (int idx = tid; idx < 121; idx += nthr) {
        int r = idx / 11, c = idx % 11;
        aug[r][c] = 11.0 * G[0][r][c] + G[1][r][c] + G[2][r][c] + ((r == c) ? 1.0 : 0.0);
    }
    if (tid < 44) {
        int r = tid / 11, j = tid % 11;
        const float* src = (r == 0) ? P : (r == 1) ? Pd : (r == 2) ? (P + 99 * 11) : (Pd + 99 * 11);
        double v = (double)src[j];
        aug[j][11 + r] = v;
        aug[11 + r][j] = v;
    }
    if (tid < 15) aug[tid][15 + tid] = 1.0;
    __syncthreads();
    gj_inv(aug, 15, fac, &piv, tid, nthr);
    if (tid < 121) { int j = tid / 11, k = tid % 11; ws[F_OFF + tid] = (float)aug[j][15 + k]; }
    if (tid < 44)  { int j = tid / 4,  k = tid % 4;  ws[G4_OFF + tid] = (float)aug[j][15 + 11 + k]; }
}

__global__ __launch_bounds__(128) void solve_kernel(
    const float* __restrict__ P, const float* __restrict__ Pd, const float* __restrict__ Pdd,
    const float* __restrict__ ise, const float* __restrict__ term, const float* __restrict__ via,
    const float* __restrict__ obs, const float* __restrict__ tgt, const float* __restrict__ dtb,
    const float* __restrict__ ws, float* __restrict__ out)
{
    __shared__ float sP[NVARS][101], sPd[NVARS][101], sPdd[NVARS][101];
    __shared__ float wb[6][101];
    __shared__ float cst[WS_FLOATS];
    __shared__ float coef[2][NVARS], lam[2][NVARS], cbar[2][NVARS], mlin[2][NVARS];
    __shared__ float Dred[6][NVARS];
    __shared__ float beq[2][4];
    __shared__ float sobs[2][NOBS];
    __shared__ float stgt[6];

    const int b = blockIdx.x;
    const int tid = threadIdx.x;

    // bases -> LDS, transposed [k][t]
    for (int idx = tid; idx < NUMT * NVARS; idx += 128) {
        int t = idx / NVARS, k = idx % NVARS;
        sP[k][t] = P[idx]; sPd[k][t] = Pd[idx]; sPdd[k][t] = Pdd[idx];
    }
    for (int idx = tid; idx < WS_FLOATS; idx += 128) cst[idx] = ws[idx];
    if (tid < 20) sobs[tid / 10][tid % 10] = obs[b * 20 + tid];
    if (tid == 0) {
        beq[0][0] = 0.f; beq[0][1] = ise[b*4+2]; beq[0][2] = term[b*4+0]; beq[0][3] = term[b*4+2];
        beq[1][0] = 0.f; beq[1][1] = ise[b*4+3]; beq[1][2] = term[b*4+1]; beq[1][3] = term[b*4+3];
        stgt[0] = tgt[b*4+0]; stgt[1] = tgt[b*4+2];   // x0, vx
        stgt[2] = tgt[b*4+1]; stgt[3] = tgt[b*4+3];   // y0, vy
        stgt[4] = dtb[b*2+0]; stgt[5] = dtb[b*2+1];   // dmin, dmax
    }
    __syncthreads();
    // c_bar = E @ [0, v0, xterm, vterm, via0, via1]; init coef = c_bar, lam = 0
    if (tid < 22) {
        int a = tid / 11, j = tid % 11;
        float bi0 = 0.f, bi1 = beq[a][1], bi2 = beq[a][2], bi3 = beq[a][3];
        float bi4 = via[b*4 + 2*a + 0], bi5 = via[b*4 + 2*a + 1];
        const float* E = &cst[E_OFF + j * 6];
        float s = E[0]*bi0 + E[1]*bi1 + E[2]*bi2 + E[3]*bi3 + E[4]*bi4 + E[5]*bi5;
        cbar[a][j] = s; coef[a][j] = s; lam[a][j] = 0.f;
    }
    __syncthreads();

    for (int it = 0; it < MAXIT; ++it) {
        // ---- phase A: per-time-point nonlinear projections -> 6 weight vectors
        if (tid < NUMT) {
            const int t = tid;
            float x=0,y=0,xd=0,yd=0,xdd=0,ydd=0;
            #pragma unroll
            for (int k = 0; k < NVARS; ++k) {
                float cxk = coef[0][k], cyk = coef[1][k];
                float p = sP[k][t], pd = sPd[k][t], pdd = sPdd[k][t];
                x += cxk*p;   y += cyk*p;
                xd += cxk*pd; yd += cyk*pd;
                xdd += cxk*pdd; ydd += cyk*pdd;
            }
            // obstacles: cos/sin(atan2) = normalized components
            float Sbx = 0.f, Sby = 0.f;
            #pragma unroll
            for (int o = 0; o < NOBS; ++o) {
                float ox = sobs[0][o], oy = sobs[1][o];
                float wc = x - ox, wsv = y - oy;
                float sn = wsv * 0.4f, cn = wc * 0.4f;   // A_OBS = B_OBS = 0.4
                float h2 = sn*sn + cn*cn;
                float rin = rsqrtf(fmaxf(h2, 1e-30f));
                float ca = cn * rin, sa = sn * rin;
                float c1 = 0.16f*ca*ca + 0.16f*sa*sa;
                float c2 = 0.4f*wc*ca + 0.4f*wsv*sa;
                float d = fmaxf(1.f, c2 / fmaxf(c1, 1e-30f));
                Sbx += ox + 0.4f*d*ca;
                Sby += oy + 0.4f*d*sa;
            }
            // velocity / acceleration / target
            float rv = sqrtf(xd*xd + yd*yd);
            float fv = fminf(fmaxf(rv, 0.1f), 2.0f) / fmaxf(rv, 1e-30f);
            float ra = sqrtf(xdd*xdd + ydd*ydd);
            float fa = fminf(ra, 2.0f) / fmaxf(ra, 1e-30f);
            float tt = (float)t * (5.0f / 99.0f);
            float xt = stgt[0] + stgt[1]*tt, yt = stgt[2] + stgt[3]*tt;
            float wct = x - xt, wst = y - yt;
            float rt = sqrtf(wct*wct + wst*wst);
            float ftg = fminf(fmaxf(rt, stgt[4]), stgt[5]) / fmaxf(rt, 1e-30f);
            wb[0][t] = Sbx + xt + wct*ftg;   // b_ox-sum + b_tx   (P weight, x)
            wb[1][t] = xd * fv;              // d_v cv            (Pd weight, x)
            wb[2][t] = xdd * fa;             // d_a cA            (Pdd weight, x)
            wb[3][t] = Sby + yt + wst*ftg;
            wb[4][t] = yd * fv;
            wb[5][t] = ydd * fa;
        }
        __syncthreads();
        // ---- phase B: 66 length-100 basis dots
        if (tid < 66) {
            int wi = tid % 6, j = tid / 6;
            int q = wi % 3;
            const float (*Bq)[101] = (q == 0) ? sP : (q == 1) ? sPd : sPdd;
            float s = 0.f;
            for (int t = 0; t < NUMT; ++t) s += wb[wi][t] * Bq[j][t];
            Dred[wi][j] = s;
        }
        __syncthreads();
        // ---- phase C: dual update + linear term (res dots via Gram matvecs)
        if (tid < 22) {
            int a = tid / 11, j = tid % 11;
            float d4=0.f, d5=0.f, d6=0.f;
            #pragma unroll
            for (int k = 0; k < 11; ++k) {
                float ck = coef[a][k];
                d4 += ck * cst[GP_OFF   + k*11 + j];
                d5 += ck * cst[GPD_OFF  + k*11 + j];
                d6 += ck * cst[GPDD_OFF + k*11 + j];
            }
            int i0 = 3*a;
            float D0 = Dred[i0][j], D1 = Dred[i0+1][j], D2 = Dred[i0+2][j];
            float l = lam[a][j];
            l -= (11.f*d4 - D0) + (d5 - D1) + (d6 - D2);
            lam[a][j] = l;
            mlin[a][j] = l + D0 + D1 + D2 + cbar[a][j];   // = -lin
        }
        __syncthreads();
        // ---- phase D: new coefficients = inv_opt-blocks @ [-lin, b_eq]
        if (tid < 22) {
            int a = tid / 11, j = tid % 11;
            float s = 0.f;
            #pragma unroll
            for (int k = 0; k < 11; ++k) s += cst[F_OFF + j*11 + k] * mlin[a][k];
            #pragma unroll
            for (int k = 0; k < 4; ++k)  s += cst[G4_OFF + j*4 + k] * beq[a][k];
            coef[a][j] = s;
        }
        __syncthreads();
    }

    if (tid < 22) out[b * 22 + tid] = coef[tid / 11][tid % 11];
}

extern "C" void kernel_launch(void* const* d_in, const int* in_sizes, int n_in,
                              void* d_out, int out_size, void* d_ws, size_t ws_size,
                              hipStream_t stream)
{
    const float* P    = (const float*)d_in[0];
    const float* Pd   = (const float*)d_in[1];
    const float* Pdd  = (const float*)d_in[2];
    const float* ise  = (const float*)d_in[3];
    const float* term = (const float*)d_in[4];
    const float* via  = (const float*)d_in[5];
    const float* obs  = (const float*)d_in[6];
    const float* tgt  = (const float*)d_in[7];
    const float* dtb  = (const float*)d_in[8];
    float* ws  = (float*)d_ws;
    float* out = (float*)d_out;

    const int B = in_sizes[3] / 4;   // 2048

    hipLaunchKernelGGL(setup_kernel, dim3(1), dim3(128), 0, stream, P, Pd, Pdd, ws);
    hipLaunchKernelGGL(solve_kernel, dim3(B), dim3(128), 0, stream,
                       P, Pd, Pdd, ise, term, via, obs, tgt, dtb, ws, out);
}

// Round 3
// 351.219 us; speedup vs baseline: 1.0109x; 1.0109x over previous
//
#include <hip/hip_runtime.h>
#include <math.h>

#define NVARS 11
#define NUMT  100
#define NOBS  10
#define MAXIT 50

// workspace layout (floats) — identical to r1
#define E_OFF    0      // inv_init[:11,11:17]  11x6
#define F_OFF    66     // inv_opt[:11,:11]     11x11
#define G4_OFF   187    // inv_opt[:11,11:15]   11x4
#define GP_OFF   231    // P^T P                11x11
#define GPD_OFF  352    // Pd^T Pd
#define GPDD_OFF 473    // Pdd^T Pdd
#define WS_FLOATS 594

__device__ void gj_inv(double (*aug)[34], int N, double* fac, int* piv, int tid, int nthr)
{
    for (int k = 0; k < N; ++k) {
        if (tid == 0) {
            int p = k; double best = fabs(aug[k][k]);
            for (int r = k + 1; r < N; ++r) { double v = fabs(aug[r][k]); if (v > best) { best = v; p = r; } }
            *piv = p;
        }
        __syncthreads();
        int p = *piv;
        if (p != k) {
            for (int c = tid; c < 2 * N; c += nthr) { double t = aug[k][c]; aug[k][c] = aug[p][c]; aug[p][c] = t; }
        }
        __syncthreads();
        double pv = aug[k][k];
        __syncthreads();
        for (int c = tid; c < 2 * N; c += nthr) aug[k][c] /= pv;
        __syncthreads();
        if (tid < N) fac[tid] = aug[tid][k];
        __syncthreads();
        for (int idx = tid; idx < N * 2 * N; idx += nthr) {
            int r = idx / (2 * N), c = idx % (2 * N);
            if (r != k) aug[r][c] -= fac[r] * aug[k][c];
        }
        __syncthreads();
    }
}

__global__ __launch_bounds__(128) void setup_kernel(const float* __restrict__ P,
                                                    const float* __restrict__ Pd,
                                                    const float* __restrict__ Pdd,
                                                    float* __restrict__ ws)
{
    __shared__ double G[3][NVARS][NVARS];
    __shared__ double aug[17][34];
    __shared__ double fac[17];
    __shared__ int piv;
    const int tid = threadIdx.x, nthr = 128;

    // Gram matrices in fp64
    for (int idx = tid; idx < 3 * 121; idx += nthr) {
        int q = idx / 121, rem = idx % 121, r = rem / 11, c = rem % 11;
        const float* B = (q == 0) ? P : (q == 1) ? Pd : Pdd;
        double s = 0.0;
        for (int t = 0; t < NUMT; ++t) s += (double)B[t * 11 + r] * (double)B[t * 11 + c];
        G[q][r][c] = s;
    }
    __syncthreads();
    for (int idx = tid; idx < 3 * 121; idx += nthr) ws[GP_OFF + idx] = (float)((&G[0][0][0])[idx]);

    // ---- inv_init: KKT [Pdd^T Pdd, A^T; A, 0], A rows = P[0],Pd[0],P[99],Pd[99],P[49],P[74]
    for (int idx = tid; idx < 17 * 34; idx += nthr) aug[idx / 34][idx % 34] = 0.0;
    __syncthreads();
    for (int idx = tid; idx < 121; idx += nthr) aug[idx / 11][idx % 11] = G[2][idx / 11][idx % 11];
    if (tid < 66) {
        int r = tid / 11, j = tid % 11;
        const float* src = (r == 0) ? P : (r == 1) ? Pd : (r == 2) ? (P + 99 * 11) : (r == 3) ? (Pd + 99 * 11)
                           : (r == 4) ? (P + 49 * 11) : (P + 74 * 11);
        double v = (double)src[j];
        aug[j][11 + r] = v;
        aug[11 + r][j] = v;
    }
    if (tid < 17) aug[tid][17 + tid] = 1.0;
    __syncthreads();
    gj_inv(aug, 17, fac, &piv, tid, nthr);
    if (tid < 66) { int j = tid / 6, k = tid % 6; ws[E_OFF + tid] = (float)aug[j][17 + 11 + k]; }
    __syncthreads();

    // ---- inv_opt: cost = 11*GP + GPd + GPdd + I ; A rows = P[0],Pd[0],P[99],Pd[99]
    for (int idx = tid; idx < 17 * 34; idx += nthr) aug[idx / 34][idx % 34] = 0.0;
    __syncthreads();
    for (int idx = tid; idx < 121; idx += nthr) {
        int r = idx / 11, c = idx % 11;
        aug[r][c] = 11.0 * G[0][r][c] + G[1][r][c] + G[2][r][c] + ((r == c) ? 1.0 : 0.0);
    }
    if (tid < 44) {
        int r = tid / 11, j = tid % 11;
        const float* src = (r == 0) ? P : (r == 1) ? Pd : (r == 2) ? (P + 99 * 11) : (Pd + 99 * 11);
        double v = (double)src[j];
        aug[j][11 + r] = v;
        aug[11 + r][j] = v;
    }
    if (tid < 15) aug[tid][15 + tid] = 1.0;
    __syncthreads();
    gj_inv(aug, 15, fac, &piv, tid, nthr);
    if (tid < 121) { int j = tid / 11, k = tid % 11; ws[F_OFF + tid] = (float)aug[j][15 + k]; }
    if (tid < 44)  { int j = tid / 4,  k = tid % 4;  ws[G4_OFF + tid] = (float)aug[j][15 + 11 + k]; }
}

// solve: 256 threads = 2 batch elements x 128 lanes; math is r1-verbatim per element
__global__ __launch_bounds__(256, 7) void solve_kernel(
    const float* __restrict__ P, const float* __restrict__ Pd, const float* __restrict__ Pdd,
    const float* __restrict__ ise, const float* __restrict__ term, const float* __restrict__ via,
    const float* __restrict__ obs, const float* __restrict__ tgt, const float* __restrict__ dtb,
    const float* __restrict__ ws, float* __restrict__ out, int Btot)
{
    __shared__ float sBc[NVARS][301];    // [j][q*100+t], q = 0:P 1:Pd 2:Pdd
    __shared__ float cst[WS_FLOATS];
    __shared__ float wbc[2][2][304];     // [elem][axis][q*100+t]
    __shared__ float Dred[2][6][12];
    __shared__ float mlin[2][2][12];
    __shared__ float scoef[2][2][12];
    __shared__ float beqs[2][2][4];
    __shared__ float sobs[2][2][NOBS];
    __shared__ float stgt[2][6];

    const int tid = threadIdx.x;
    const int l = tid & 127;             // element-local lane
    const int e = tid >> 7;              // element slot
    int b = blockIdx.x * 2 + e;
    const bool real = (b < Btot);
    if (!real) b = Btot - 1;             // benign duplicate compute, write guarded

    // ---- stage LDS
    for (int idx = tid; idx < NVARS * 301; idx += 256) {
        int j = idx / 301, r = idx % 301;
        float v = 0.f;
        if (r < 300) {
            int q = r / 100, t = r % 100;
            const float* Bq = (q == 0) ? P : (q == 1) ? Pd : Pdd;
            v = Bq[t * 11 + j];
        }
        sBc[j][r] = v;
    }
    for (int idx = tid; idx < WS_FLOATS; idx += 256) cst[idx] = ws[idx];
    if (l < 20) sobs[e][l / 10][l % 10] = obs[b * 20 + l];
    if (l == 0) {
        beqs[e][0][0] = 0.f; beqs[e][0][1] = ise[b*4+2]; beqs[e][0][2] = term[b*4+0]; beqs[e][0][3] = term[b*4+2];
        beqs[e][1][0] = 0.f; beqs[e][1][1] = ise[b*4+3]; beqs[e][1][2] = term[b*4+1]; beqs[e][1][3] = term[b*4+3];
        stgt[e][0] = tgt[b*4+0]; stgt[e][1] = tgt[b*4+2];   // x0, vx
        stgt[e][2] = tgt[b*4+1]; stgt[e][3] = tgt[b*4+3];   // y0, vy
        stgt[e][4] = dtb[b*2+0]; stgt[e][5] = dtb[b*2+1];   // dmin, dmax
    }
    __syncthreads();

    // init: c_bar = E @ [0, v0, xterm, vterm, via0, via1] — r1-verbatim
    const int ca = l / 11, cj = l % 11;
    float lm = 0.f, cb = 0.f;
    if (l < 22) {
        float bi0 = 0.f, bi1 = beqs[e][ca][1], bi2 = beqs[e][ca][2], bi3 = beqs[e][ca][3];
        float bi4 = via[b*4 + 2*ca + 0], bi5 = via[b*4 + 2*ca + 1];
        const float* E = &cst[E_OFF + cj * 6];
        float s = E[0]*bi0 + E[1]*bi1 + E[2]*bi2 + E[3]*bi3 + E[4]*bi4 + E[5]*bi5;
        cb = s; scoef[e][ca][cj] = s;
    }
    __syncthreads();

    // phase invariants
    const float* ptA = &sBc[0][l];                     // + k*301 (+100/+200)
    float* pwA = &wbc[e][0][l];                        // + axis*304 + q*100
    const int wi = l % 6, bjj = l / 6;                 // phase-B task (l<66)
    const float* pbB = &sBc[0][0] + bjj * 301 + (wi % 3) * 100;
    const float* pwB = &wbc[e][wi / 3][(wi % 3) * 100];

    for (int it = 0; it < MAXIT; ++it) {
        // ---- phase A: r1-verbatim per-point projections
        if (l < NUMT) {
            const int t = l;
            float x=0,y=0,xd=0,yd=0,xdd=0,ydd=0;
            #pragma unroll
            for (int k = 0; k < NVARS; ++k) {
                float cxk = scoef[e][0][k], cyk = scoef[e][1][k];
                float p = ptA[k*301], pd = ptA[k*301 + 100], pdd = ptA[k*301 + 200];
                x += cxk*p;   y += cyk*p;
                xd += cxk*pd; yd += cyk*pd;
                xdd += cxk*pdd; ydd += cyk*pdd;
            }
            float Sbx = 0.f, Sby = 0.f;
            #pragma unroll
            for (int o = 0; o < NOBS; ++o) {
                float ox = sobs[e][0][o], oy = sobs[e][1][o];
                float wc = x - ox, wsv = y - oy;
                float sn = wsv * 0.4f, cn = wc * 0.4f;
                float h2 = sn*sn + cn*cn;
                float rin = rsqrtf(fmaxf(h2, 1e-30f));
                float cav = cn * rin, sav = sn * rin;
                float c1 = 0.16f*cav*cav + 0.16f*sav*sav;
                float c2 = 0.4f*wc*cav + 0.4f*wsv*sav;
                float d = fmaxf(1.f, c2 / fmaxf(c1, 1e-30f));
                Sbx += ox + 0.4f*d*cav;
                Sby += oy + 0.4f*d*sav;
            }
            float rv = sqrtf(xd*xd + yd*yd);
            float fv = fminf(fmaxf(rv, 0.1f), 2.0f) / fmaxf(rv, 1e-30f);
            float ra = sqrtf(xdd*xdd + ydd*ydd);
            float fa = fminf(ra, 2.0f) / fmaxf(ra, 1e-30f);
            float tt = (float)t * (5.0f / 99.0f);
            float xt = stgt[e][0] + stgt[e][1]*tt, yt = stgt[e][2] + stgt[e][3]*tt;
            float wct = x - xt, wst = y - yt;
            float rt = sqrtf(wct*wct + wst*wst);
            float ftg = fminf(fmaxf(rt, stgt[e][4]), stgt[e][5]) / fmaxf(rt, 1e-30f);
            pwA[0]   = Sbx + xt + wct*ftg;   // wb[0]: P-weight, x
            pwA[100] = xd * fv;              // wb[1]
            pwA[200] = xdd * fa;             // wb[2]
            pwA[304] = Sby + yt + wst*ftg;   // wb[3]
            pwA[404] = yd * fv;              // wb[4]
            pwA[504] = ydd * fa;             // wb[5]
        }
        __syncthreads();

        // ---- phase B: 66 straight 100-term dots (r1 order)
        if (l < 66) {
            float s = 0.f;
            for (int t = 0; t < NUMT; ++t) s += pwB[t] * pbB[t];
            Dred[e][wi][bjj] = s;
        }
        __syncthreads();

        // ---- phase C: dual update via Gram matvecs (r1-verbatim)
        if (l < 22) {
            float d4=0.f, d5=0.f, d6=0.f;
            #pragma unroll
            for (int k = 0; k < 11; ++k) {
                float ck = scoef[e][ca][k];
                d4 += ck * cst[GP_OFF   + k*11 + cj];
                d5 += ck * cst[GPD_OFF  + k*11 + cj];
                d6 += ck * cst[GPDD_OFF + k*11 + cj];
            }
            int i0 = 3*ca;
            float D0 = Dred[e][i0][cj], D1 = Dred[e][i0+1][cj], D2 = Dred[e][i0+2][cj];
            lm -= (11.f*d4 - D0) + (d5 - D1) + (d6 - D2);
            mlin[e][ca][cj] = lm + D0 + D1 + D2 + cb;
        }
        // no barrier: phase C/D producers+consumers are lanes l<22 of the same wave

        // ---- phase D: coef = F @ mlin + G4 @ beq (r1-verbatim)
        if (l < 22) {
            float s = 0.f;
            #pragma unroll
            for (int k = 0; k < 11; ++k) s += cst[F_OFF + cj*11 + k] * mlin[e][ca][k];
            #pragma unroll
            for (int k = 0; k < 4; ++k)  s += cst[G4_OFF + cj*4 + k] * beqs[e][ca][k];
            scoef[e][ca][cj] = s;
        }
        __syncthreads();
    }

    if (real && l < 22) out[b * 22 + l] = scoef[e][ca][cj];
}

extern "C" void kernel_launch(void* const* d_in, const int* in_sizes, int n_in,
                              void* d_out, int out_size, void* d_ws, size_t ws_size,
                              hipStream_t stream)
{
    const float* P    = (const float*)d_in[0];
    const float* Pd   = (const float*)d_in[1];
    const float* Pdd  = (const float*)d_in[2];
    const float* ise  = (const float*)d_in[3];
    const float* term = (const float*)d_in[4];
    const float* via  = (const float*)d_in[5];
    const float* obs  = (const float*)d_in[6];
    const float* tgt  = (const float*)d_in[7];
    const float* dtb  = (const float*)d_in[8];
    float* ws  = (float*)d_ws;
    float* out = (float*)d_out;

    const int B = in_sizes[3] / 4;   // 2048
    const int nblk = (B + 1) / 2;

    hipLaunchKernelGGL(setup_kernel, dim3(1), dim3(128), 0, stream, P, Pd, Pdd, ws);
    hipLaunchKernelGGL(solve_kernel, dim3(nblk), dim3(256), 0, stream,
                       P, Pd, Pdd, ise, term, via, obs, tgt, dtb, ws, out, B);
}

// Round 4
// 263.577 us; speedup vs baseline: 1.3471x; 1.3325x over previous
//
#include <hip/hip_runtime.h>
#include <math.h>

#define NVARS 11
#define NUMT  100
#define NOBS  10
#define MAXIT 50

// workspace layout (floats) — identical to r1/r3
#define E_OFF    0      // inv_init[:11,11:17]  11x6
#define F_OFF    66     // inv_opt[:11,:11]     11x11
#define G4_OFF   187    // inv_opt[:11,11:15]   11x4
#define GP_OFF   231    // P^T P                11x11
#define GPD_OFF  352    // Pd^T Pd
#define GPDD_OFF 473    // Pdd^T Pdd
#define WS_FLOATS 594

__device__ void gj_inv(double (*aug)[34], int N, double* fac, int* piv, int tid, int nthr)
{
    for (int k = 0; k < N; ++k) {
        if (tid == 0) {
            int p = k; double best = fabs(aug[k][k]);
            for (int r = k + 1; r < N; ++r) { double v = fabs(aug[r][k]); if (v > best) { best = v; p = r; } }
            *piv = p;
        }
        __syncthreads();
        int p = *piv;
        if (p != k) {
            for (int c = tid; c < 2 * N; c += nthr) { double t = aug[k][c]; aug[k][c] = aug[p][c]; aug[p][c] = t; }
        }
        __syncthreads();
        double pv = aug[k][k];
        __syncthreads();
        for (int c = tid; c < 2 * N; c += nthr) aug[k][c] /= pv;
        __syncthreads();
        if (tid < N) fac[tid] = aug[tid][k];
        __syncthreads();
        for (int idx = tid; idx < N * 2 * N; idx += nthr) {
            int r = idx / (2 * N), c = idx % (2 * N);
            if (r != k) aug[r][c] -= fac[r] * aug[k][c];
        }
        __syncthreads();
    }
}

__global__ __launch_bounds__(128) void setup_kernel(const float* __restrict__ P,
                                                    const float* __restrict__ Pd,
                                                    const float* __restrict__ Pdd,
                                                    float* __restrict__ ws)
{
    __shared__ double G[3][NVARS][NVARS];
    __shared__ double aug[17][34];
    __shared__ double fac[17];
    __shared__ int piv;
    const int tid = threadIdx.x, nthr = 128;

    for (int idx = tid; idx < 3 * 121; idx += nthr) {
        int q = idx / 121, rem = idx % 121, r = rem / 11, c = rem % 11;
        const float* B = (q == 0) ? P : (q == 1) ? Pd : Pdd;
        double s = 0.0;
        for (int t = 0; t < NUMT; ++t) s += (double)B[t * 11 + r] * (double)B[t * 11 + c];
        G[q][r][c] = s;
    }
    __syncthreads();
    for (int idx = tid; idx < 3 * 121; idx += nthr) ws[GP_OFF + idx] = (float)((&G[0][0][0])[idx]);

    for (int idx = tid; idx < 17 * 34; idx += nthr) aug[idx / 34][idx % 34] = 0.0;
    __syncthreads();
    for (int idx = tid; idx < 121; idx += nthr) aug[idx / 11][idx % 11] = G[2][idx / 11][idx % 11];
    if (tid < 66) {
        int r = tid / 11, j = tid % 11;
        const float* src = (r == 0) ? P : (r == 1) ? Pd : (r == 2) ? (P + 99 * 11) : (r == 3) ? (Pd + 99 * 11)
                           : (r == 4) ? (P + 49 * 11) : (P + 74 * 11);
        double v = (double)src[j];
        aug[j][11 + r] = v;
        aug[11 + r][j] = v;
    }
    if (tid < 17) aug[tid][17 + tid] = 1.0;
    __syncthreads();
    gj_inv(aug, 17, fac, &piv, tid, nthr);
    if (tid < 66) { int j = tid / 6, k = tid % 6; ws[E_OFF + tid] = (float)aug[j][17 + 11 + k]; }
    __syncthreads();

    for (int idx = tid; idx < 17 * 34; idx += nthr) aug[idx / 34][idx % 34] = 0.0;
    __syncthreads();
    for (int idx = tid; idx < 121; idx += nthr) {
        int r = idx / 11, c = idx % 11;
        aug[r][c] = 11.0 * G[0][r][c] + G[1][r][c] + G[2][r][c] + ((r == c) ? 1.0 : 0.0);
    }
    if (tid < 44) {
        int r = tid / 11, j = tid % 11;
        const float* src = (r == 0) ? P : (r == 1) ? Pd : (r == 2) ? (P + 99 * 11) : (Pd + 99 * 11);
        double v = (double)src[j];
        aug[j][11 + r] = v;
        aug[11 + r][j] = v;
    }
    if (tid < 15) aug[tid][15 + tid] = 1.0;
    __syncthreads();
    gj_inv(aug, 15, fac, &piv, tid, nthr);
    if (tid < 121) { int j = tid / 11, k = tid % 11; ws[F_OFF + tid] = (float)aug[j][15 + k]; }
    if (tid < 44)  { int j = tid / 4,  k = tid % 4;  ws[G4_OFF + tid] = (float)aug[j][15 + 11 + k]; }
}

__device__ __forceinline__ float sbcast(float v) {
    return __int_as_float(__builtin_amdgcn_readfirstlane(__float_as_int(v)));
}

// solve: 256 threads = 2 batch elements x 128 lanes
__global__ __launch_bounds__(256, 4) void solve_kernel(
    const float* __restrict__ P, const float* __restrict__ Pd, const float* __restrict__ Pdd,
    const float* __restrict__ ise, const float* __restrict__ term, const float* __restrict__ via,
    const float* __restrict__ obs, const float* __restrict__ tgt, const float* __restrict__ dtb,
    const float* __restrict__ ws, float* __restrict__ out, int Btot)
{
    __shared__ __align__(16) float sBc[NVARS][304];   // [j][q*100+t]
    __shared__ __align__(16) float wbc[2][2][304];    // [elem][axis][q*100+t]
    __shared__ float cst[WS_FLOATS];
    __shared__ float Dred[2][6][12];
    __shared__ float mlin[2][2][12];
    __shared__ float scoef[2][2][12];
    __shared__ float beqs[2][2][4];
    __shared__ float sobs[2][2][NOBS];
    __shared__ float stgt[2][6];

    const int tid = threadIdx.x;
    const int l = tid & 127;
    const int e = tid >> 7;
    int b = blockIdx.x * 2 + e;
    const bool real = (b < Btot);
    if (!real) b = Btot - 1;

    // ---- stage LDS
    for (int idx = tid; idx < NVARS * 304; idx += 256) {
        int j = idx / 304, r = idx % 304;
        float v = 0.f;
        if (r < 300) {
            int q = r / 100, t = r % 100;
            const float* Bq = (q == 0) ? P : (q == 1) ? Pd : Pdd;
            v = Bq[t * 11 + j];
        }
        sBc[j][r] = v;
    }
    for (int idx = tid; idx < WS_FLOATS; idx += 256) cst[idx] = ws[idx];
    if (l < 20) sobs[e][l / 10][l % 10] = obs[b * 20 + l];
    if (l == 0) {
        beqs[e][0][0] = 0.f; beqs[e][0][1] = ise[b*4+2]; beqs[e][0][2] = term[b*4+0]; beqs[e][0][3] = term[b*4+2];
        beqs[e][1][0] = 0.f; beqs[e][1][1] = ise[b*4+3]; beqs[e][1][2] = term[b*4+1]; beqs[e][1][3] = term[b*4+3];
        stgt[e][0] = tgt[b*4+0]; stgt[e][1] = tgt[b*4+2];
        stgt[e][2] = tgt[b*4+1]; stgt[e][3] = tgt[b*4+3];
        stgt[e][4] = dtb[b*2+0]; stgt[e][5] = dtb[b*2+1];
    }
    __syncthreads();

    // init c_bar (r1-verbatim)
    const int ca = l / 11, cj = l % 11;
    float lm = 0.f, cb = 0.f;
    if (l < 22) {
        float bi0 = 0.f, bi1 = beqs[e][ca][1], bi2 = beqs[e][ca][2], bi3 = beqs[e][ca][3];
        float bi4 = via[b*4 + 2*ca + 0], bi5 = via[b*4 + 2*ca + 1];
        const float* E = &cst[E_OFF + cj * 6];
        float s = E[0]*bi0 + E[1]*bi1 + E[2]*bi2 + E[3]*bi3 + E[4]*bi4 + E[5]*bi5;
        cb = s; scoef[e][ca][cj] = s;
    }

    // ---- iteration-invariant caches
    // basis values for this lane's time point -> VGPRs (lanes l<100)
    float rP[NVARS], rPd[NVARS], rPdd[NVARS];
    {
        const int t = (l < NUMT) ? l : 0;
        #pragma unroll
        for (int k = 0; k < NVARS; ++k) {
            rP[k]   = sBc[k][t];
            rPd[k]  = sBc[k][t + 100];
            rPdd[k] = sBc[k][t + 200];
        }
    }
    // obstacles / target params -> SGPRs (wave-uniform: waves 0,1 are e=0; waves 2,3 are e=1)
    float obx[NOBS], oby[NOBS];
    #pragma unroll
    for (int o = 0; o < NOBS; ++o) {
        obx[o] = sbcast(sobs[e][0][o]);
        oby[o] = sbcast(sobs[e][1][o]);
    }
    const float tg0 = sbcast(stgt[e][0]), tg1 = sbcast(stgt[e][1]);
    const float tg2 = sbcast(stgt[e][2]), tg3 = sbcast(stgt[e][3]);
    const float tg4 = sbcast(stgt[e][4]), tg5 = sbcast(stgt[e][5]);

    float* pwA = &wbc[e][0][l];              // + axis*304 + q*100
    const int wi = l % 6, bjj = l / 6;       // phase-B task (l<66)
    const float4* pbB = (const float4*)(&sBc[0][0] + bjj * 304 + (wi % 3) * 100);
    const float4* pwB = (const float4*)(&wbc[e][wi / 3][(wi % 3) * 100]);
    __syncthreads();

    for (int it = 0; it < MAXIT; ++it) {
        // ---- phase A
        if (l < NUMT) {
            float x=0,y=0,xd=0,yd=0,xdd=0,ydd=0;
            #pragma unroll
            for (int k = 0; k < NVARS; ++k) {
                float cxk = scoef[e][0][k], cyk = scoef[e][1][k];
                x += cxk*rP[k];   y += cyk*rP[k];
                xd += cxk*rPd[k]; yd += cyk*rPd[k];
                xdd += cxk*rPdd[k]; ydd += cyk*rPdd[k];
            }
            // obstacles, div-free: b = o + d*max(1, 0.4*rsqrt(R2))
            float Sbx = 0.f, Sby = 0.f;
            #pragma unroll
            for (int o = 0; o < NOBS; ++o) {
                float dx = x - obx[o], dy = y - oby[o];
                float r2 = dx*dx + dy*dy;
                float f  = fmaxf(1.0f, 0.4f * rsqrtf(fmaxf(r2, 1e-30f)));
                Sbx += fmaf(dx, f, obx[o]);
                Sby += fmaf(dy, f, oby[o]);
            }
            // vel/acc/target: r1-verbatim
            float rv = sqrtf(xd*xd + yd*yd);
            float fv = fminf(fmaxf(rv, 0.1f), 2.0f) / fmaxf(rv, 1e-30f);
            float ra = sqrtf(xdd*xdd + ydd*ydd);
            float fa = fminf(ra, 2.0f) / fmaxf(ra, 1e-30f);
            float tt = (float)l * (5.0f / 99.0f);
            float xt = tg0 + tg1*tt, yt = tg2 + tg3*tt;
            float wct = x - xt, wst = y - yt;
            float rt = sqrtf(wct*wct + wst*wst);
            float ftg = fminf(fmaxf(rt, tg4), tg5) / fmaxf(rt, 1e-30f);
            pwA[0]   = Sbx + xt + wct*ftg;
            pwA[100] = xd * fv;
            pwA[200] = xdd * fa;
            pwA[304] = Sby + yt + wst*ftg;
            pwA[404] = yd * fv;
            pwA[504] = ydd * fa;
        }
        __syncthreads();

        // ---- phase B: 66 dots, float4 LDS reads, exact t-order accumulate
        if (l < 66) {
            float s = 0.f;
            #pragma unroll
            for (int i = 0; i < 25; ++i) {
                float4 a = pbB[i], w = pwB[i];
                s += w.x * a.x; s += w.y * a.y; s += w.z * a.z; s += w.w * a.w;
            }
            Dred[e][wi][bjj] = s;
        }
        __syncthreads();

        // ---- phase C (r1-verbatim)
        if (l < 22) {
            float d4=0.f, d5=0.f, d6=0.f;
            #pragma unroll
            for (int k = 0; k < 11; ++k) {
                float ck = scoef[e][ca][k];
                d4 += ck * cst[GP_OFF   + k*11 + cj];
                d5 += ck * cst[GPD_OFF  + k*11 + cj];
                d6 += ck * cst[GPDD_OFF + k*11 + cj];
            }
            int i0 = 3*ca;
            float D0 = Dred[e][i0][cj], D1 = Dred[e][i0+1][cj], D2 = Dred[e][i0+2][cj];
            lm -= (11.f*d4 - D0) + (d5 - D1) + (d6 - D2);
            mlin[e][ca][cj] = lm + D0 + D1 + D2 + cb;
        }
        // producers/consumers of C->D are lanes l<22 of one wave: no barrier

        // ---- phase D (r1-verbatim)
        if (l < 22) {
            float s = 0.f;
            #pragma unroll
            for (int k = 0; k < 11; ++k) s += cst[F_OFF + cj*11 + k] * mlin[e][ca][k];
            #pragma unroll
            for (int k = 0; k < 4; ++k)  s += cst[G4_OFF + cj*4 + k] * beqs[e][ca][k];
            scoef[e][ca][cj] = s;
        }
        __syncthreads();
    }

    if (real && l < 22) out[b * 22 + l] = scoef[e][ca][cj];
}

extern "C" void kernel_launch(void* const* d_in, const int* in_sizes, int n_in,
                              void* d_out, int out_size, void* d_ws, size_t ws_size,
                              hipStream_t stream)
{
    const float* P    = (const float*)d_in[0];
    const float* Pd   = (const float*)d_in[1];
    const float* Pdd  = (const float*)d_in[2];
    const float* ise  = (const float*)d_in[3];
    const float* term = (const float*)d_in[4];
    const float* via  = (const float*)d_in[5];
    const float* obs  = (const float*)d_in[6];
    const float* tgt  = (const float*)d_in[7];
    const float* dtb  = (const float*)d_in[8];
    float* ws  = (float*)d_ws;
    float* out = (float*)d_out;

    const int B = in_sizes[3] / 4;   // 2048
    const int nblk = (B + 1) / 2;

    hipLaunchKernelGGL(setup_kernel, dim3(1), dim3(128), 0, stream, P, Pd, Pdd, ws);
    hipLaunchKernelGGL(solve_kernel, dim3(nblk), dim3(256), 0, stream,
                       P, Pd, Pdd, ise, term, via, obs, tgt, dtb, ws, out, B);
}